// Round 2
// baseline (153.547 us; speedup 1.0000x reference)
//
#include <hip/hip_runtime.h>
#include <math.h>

#define BSZ 512
#define DD 2048
#define KK 128
#define PP 5
#define NCOL (KK * PP)   // 640
#define OUTW (DD + KK)   // 2176
#define LOG2E 1.4426950408889634f

#define KSPLIT 16
#define GM 64            // m rows per block (lane dim)
#define GN 64            // n cols per block (4 waves x 16)
#define GK (DD / KSPLIT) // 128 k-depth per split
#define GBK 32           // k chunk staged in LDS
#define QSPLIT 8         // pairwise b2 chunks

// ws layout (floats):
#define WS_NORM 0
#define WS_ACTV (WS_NORM + NCOL)                 // 640
#define WS_PART (WS_ACTV + BSZ * NCOL)           // 328320
// part = 16*512*640 = 5,242,880 floats; total ~22.3 MB

// ---------------------------------------------------------------------------
// Kernel 1: column sums of theta^2 -> norm[col]. Deterministic (no memset,
// no atomics): 80 blocks x 8 cols, LDS partial reduction.
// ---------------------------------------------------------------------------
__global__ __launch_bounds__(256) void norm_kernel(const float* __restrict__ theta,
                                                   float* __restrict__ norm) {
    __shared__ float partial[32][8];   // [d-group][col]
    const int t   = threadIdx.x;
    const int c8  = blockIdx.x * 8;    // 80 blocks -> 640 cols
    const int col = c8 + (t & 7);
    const int g   = t >> 3;            // 0..31
    const float* p = theta + (size_t)g * NCOL + col;
    float s = 0.f;
#pragma unroll
    for (int j = 0; j < 64; ++j) {     // d = g + 32*j covers 0..2047
        float v = p[(size_t)j * 32 * NCOL];
        s += v * v;
    }
    partial[g][t & 7] = s;
    __syncthreads();
    if (t < 8) {
        float acc = 0.f;
#pragma unroll
        for (int gg = 0; gg < 32; ++gg) acc += partial[gg][t];
        norm[c8 + t] = acc;
    }
}

// ---------------------------------------------------------------------------
// Kernel 2: split-K GEMM, scalar-B form, software-pipelined staging.
// Wave: lane = m row, 16 n-cols per wave. A (x) in LDS (ds_read_b32,
// 2-way=free). B (theta) via wave-uniform SGPR addresses -> s_load.
// z slice KSPLIT (80 extra blocks) streams x -> out[:, :D] (pure-BW work
// overlapped under the VALU-bound GEMM blocks).
// ---------------------------------------------------------------------------
__global__ __launch_bounds__(256) void gemm_kernel(const float* __restrict__ x,
                                                   const float* __restrict__ theta,
                                                   float* __restrict__ part,
                                                   float* __restrict__ out) {
    __shared__ float xT[GBK][GM];   // [kk][m], 8 KiB

    if (blockIdx.z == KSPLIT) {
        // x -> out[:, :D] copy; 80 blocks, grid-stride over 512*512 float4
        const int bid = blockIdx.y * (NCOL / GN) + blockIdx.x;   // 0..79
        for (int i = bid * 256 + threadIdx.x; i < BSZ * (DD / 4); i += 80 * 256) {
            int r = i >> 9;
            int c = i & 511;
            float4 v = *(const float4*)&x[(size_t)r * DD + c * 4];
            *(float4*)&out[(size_t)r * OUTW + c * 4] = v;
        }
        return;
    }

    const int t    = threadIdx.x;
    const int lane = t & 63;
    const int wave = t >> 6;                 // 0..3
    const int m    = blockIdx.y * GM + lane;
    const int kz   = blockIdx.z * GK;
    const int nw = __builtin_amdgcn_readfirstlane(blockIdx.x * GN + wave * 16);

    const float* xrow = x + (size_t)m * DD;

    float acc[16] = {};

    // prefetch first chunk
    float4 v0 = *(const float4*)&xrow[kz + wave * 8];
    float4 v1 = *(const float4*)&xrow[kz + wave * 8 + 4];

    for (int kc = kz; kc < kz + GK; kc += GBK) {
        __syncthreads();   // previous chunk's LDS reads complete
        xT[wave * 8 + 0][lane] = v0.x;
        xT[wave * 8 + 1][lane] = v0.y;
        xT[wave * 8 + 2][lane] = v0.z;
        xT[wave * 8 + 3][lane] = v0.w;
        xT[wave * 8 + 4][lane] = v1.x;
        xT[wave * 8 + 5][lane] = v1.y;
        xT[wave * 8 + 6][lane] = v1.z;
        xT[wave * 8 + 7][lane] = v1.w;
        __syncthreads();

        // issue next chunk's global loads now; in flight during compute
        if (kc + GBK < kz + GK) {
            v0 = *(const float4*)&xrow[kc + GBK + wave * 8];
            v1 = *(const float4*)&xrow[kc + GBK + wave * 8 + 4];
        }

        const float* th = &theta[(size_t)kc * NCOL + nw];
#pragma unroll 4
        for (int kk = 0; kk < GBK; ++kk) {
            const float a = xT[kk][lane];
#pragma unroll
            for (int j = 0; j < 16; ++j)
                acc[j] += a * th[(size_t)kk * NCOL + j];   // wave-uniform -> s_load
        }
    }

    float* dst = part + (size_t)blockIdx.z * (BSZ * NCOL) + (size_t)m * NCOL + nw;
    *(float4*)&dst[0]  = make_float4(acc[0],  acc[1],  acc[2],  acc[3]);
    *(float4*)&dst[4]  = make_float4(acc[4],  acc[5],  acc[6],  acc[7]);
    *(float4*)&dst[8]  = make_float4(acc[8],  acc[9],  acc[10], acc[11]);
    *(float4*)&dst[12] = make_float4(acc[12], acc[13], acc[14], acc[15]);
}

// ---------------------------------------------------------------------------
// Kernel 3: reduce 16 split-K partials, fold scale = exp(lws)/norm * log2e.
// Extra 256 blocks init out[:, D:] = bias[k] - 1 (the -1 cancels the
// diagonal exp(0)=1 term pairwise will atomically add). 512*128 = 65536
// elements = 256 blocks x 256 threads.
// ---------------------------------------------------------------------------
__global__ __launch_bounds__(256) void reduce_kernel(const float* __restrict__ part,
                                                     const float* __restrict__ norm,
                                                     const float* __restrict__ lws,
                                                     const float* __restrict__ bias,
                                                     float* __restrict__ actv,
                                                     float* __restrict__ out) {
    if (blockIdx.x >= (BSZ * NCOL) / 256) {
        int i = (blockIdx.x - (BSZ * NCOL) / 256) * 256 + threadIdx.x;  // 0..65535
        int b = i >> 7;
        int k = i & 127;
        out[(size_t)b * OUTW + DD + k] = bias[k] - 1.0f;
        return;
    }
    int i   = blockIdx.x * 256 + threadIdx.x;   // 0..327679
    int col = i % NCOL;
    float s = 0.f;
#pragma unroll
    for (int q = 0; q < KSPLIT; ++q)
        s += part[(size_t)q * (BSZ * NCOL) + i];
    const float scale = __builtin_amdgcn_exp2f(lws[col] * LOG2E) *
                        __builtin_amdgcn_rsqf(norm[col]) * LOG2E;
    actv[i] = s * scale;
}

// ---------------------------------------------------------------------------
// Kernel 4: pairwise L1 -> exp2 -> partial rowsum over 64-wide b2 chunk,
// atomicAdd directly into out[:, D:] (8 adds per output element).
// Block = 128 threads, 4 b-rows each: per b2 iteration 2 DS insts feed
// 4 rows of VALU -> VALU-bound. grid (k=128, q=8) = 1024 blocks x 2 waves.
// ---------------------------------------------------------------------------
__global__ __launch_bounds__(128) void pairwise_kernel(const float* __restrict__ actv,
                                                       float* __restrict__ out) {
    const int k   = blockIdx.x;    // 0..127
    const int q   = blockIdx.y;    // 0..7
    const int tid = threadIdx.x;   // 0..127

    __shared__ float sB[64][8];    // 2 KiB, rows 32B-aligned

    for (int i = tid; i < 64 * PP; i += 128) {   // 320 entries, 3 iterations
        int r = i / PP;
        int p = i - r * PP;
        sB[r][p] = actv[(size_t)(q * 64 + r) * NCOL + k * PP + p];
    }

    float a[4][PP];
#pragma unroll
    for (int r = 0; r < 4; ++r) {
        const float* ap = &actv[(size_t)(tid + r * 128) * NCOL + k * PP];
#pragma unroll
        for (int p = 0; p < PP; ++p) a[r][p] = ap[p];
    }
    __syncthreads();

    float acc[4] = {0.f, 0.f, 0.f, 0.f};
#pragma unroll 2
    for (int j = 0; j < 64; ++j) {
        const float4 v  = *(const float4*)&sB[j][0];
        const float  v4 = sB[j][4];
#pragma unroll
        for (int r = 0; r < 4; ++r) {
            float s = fabsf(a[r][0] - v.x) + fabsf(a[r][1] - v.y) +
                      fabsf(a[r][2] - v.z) + fabsf(a[r][3] - v.w) +
                      fabsf(a[r][4] - v4);
            acc[r] += __builtin_amdgcn_exp2f(-s);   // actv pre-scaled by log2e
        }
    }

#pragma unroll
    for (int r = 0; r < 4; ++r)
        atomicAdd(&out[(size_t)(tid + r * 128) * OUTW + DD + k], acc[r]);
}

// ---------------------------------------------------------------------------
extern "C" void kernel_launch(void* const* d_in, const int* in_sizes, int n_in,
                              void* d_out, int out_size, void* d_ws, size_t ws_size,
                              hipStream_t stream) {
    const float* x     = (const float*)d_in[0];   // [512, 2048]
    const float* theta = (const float*)d_in[1];   // [2048, 128, 5]
    const float* lws   = (const float*)d_in[2];   // [128, 5]
    const float* bias  = (const float*)d_in[3];   // [128]
    float* out = (float*)d_out;                   // [512, 2176]

    float* ws   = (float*)d_ws;
    float* norm = ws + WS_NORM;
    float* actv = ws + WS_ACTV;
    float* part = ws + WS_PART;

    norm_kernel<<<80, 256, 0, stream>>>(theta, norm);
    gemm_kernel<<<dim3(NCOL / GN, BSZ / GM, KSPLIT + 1), 256, 0, stream>>>(x, theta, part, out);
    reduce_kernel<<<(BSZ * NCOL) / 256 + 256, 256, 0, stream>>>(part, norm, lws, bias, actv, out);
    pairwise_kernel<<<dim3(KK, QSPLIT), 128, 0, stream>>>(actv, out);
}

// Round 3
// 122.641 us; speedup vs baseline: 1.2520x; 1.2520x over previous
//
#include <hip/hip_runtime.h>
#include <math.h>

#define BSZ 512
#define DD 2048
#define KK 128
#define PP 5
#define NCOL (KK * PP)   // 640
#define OUTW (DD + KK)   // 2176
#define LOG2E 1.4426950408889634f

#define KSPLIT 16
#define GM 64            // m rows per block (lane dim)
#define GN 64            // n cols per block (4 waves x 16)
#define GK (DD / KSPLIT) // 128 k-depth per split
#define GBK 32           // k chunk staged in LDS
#define QSPLIT 8         // pairwise b2 chunks

// ws layout (floats):
#define WS_NORM 0
#define WS_ACTV (WS_NORM + NCOL)                      // 640
#define WS_FPART (WS_ACTV + BSZ * NCOL)               // 328320
#define WS_PART (WS_FPART + QSPLIT * KK * BSZ)        // 852608
// part = 16*512*640 = 5,242,880 floats; total ~24.4 MB

// ---------------------------------------------------------------------------
// Kernel 1: column sums of theta^2 -> norm[col]. Deterministic (no memset,
// no atomics): 80 blocks x 8 cols, LDS partial reduction.
// ---------------------------------------------------------------------------
__global__ __launch_bounds__(256) void norm_kernel(const float* __restrict__ theta,
                                                   float* __restrict__ norm) {
    __shared__ float partial[32][8];   // [d-group][col]
    const int t   = threadIdx.x;
    const int c8  = blockIdx.x * 8;    // 80 blocks -> 640 cols
    const int col = c8 + (t & 7);
    const int g   = t >> 3;            // 0..31
    const float* p = theta + (size_t)g * NCOL + col;
    float s = 0.f;
#pragma unroll
    for (int j = 0; j < 64; ++j) {     // d = g + 32*j covers 0..2047
        float v = p[(size_t)j * 32 * NCOL];
        s += v * v;
    }
    partial[g][t & 7] = s;
    __syncthreads();
    if (t < 8) {
        float acc = 0.f;
#pragma unroll
        for (int gg = 0; gg < 32; ++gg) acc += partial[gg][t];
        norm[c8 + t] = acc;
    }
}

// ---------------------------------------------------------------------------
// Kernel 2: split-K GEMM, scalar-B form, software-pipelined staging.
// Wave: lane = m row, 16 n-cols per wave. A (x) in LDS (ds_read_b32,
// 2-way=free). B (theta) via wave-uniform SGPR addresses -> s_load.
// z slice KSPLIT (80 extra blocks) streams x -> out[:, :D] (pure-BW work
// overlapped under the VALU-bound GEMM blocks).
// ---------------------------------------------------------------------------
__global__ __launch_bounds__(256) void gemm_kernel(const float* __restrict__ x,
                                                   const float* __restrict__ theta,
                                                   float* __restrict__ part,
                                                   float* __restrict__ out) {
    __shared__ float xT[GBK][GM];   // [kk][m], 8 KiB

    if (blockIdx.z == KSPLIT) {
        // x -> out[:, :D] copy; 80 blocks, grid-stride over 512*512 float4
        const int bid = blockIdx.y * (NCOL / GN) + blockIdx.x;   // 0..79
        for (int i = bid * 256 + threadIdx.x; i < BSZ * (DD / 4); i += 80 * 256) {
            int r = i >> 9;
            int c = i & 511;
            float4 v = *(const float4*)&x[(size_t)r * DD + c * 4];
            *(float4*)&out[(size_t)r * OUTW + c * 4] = v;
        }
        return;
    }

    const int t    = threadIdx.x;
    const int lane = t & 63;
    const int wave = t >> 6;                 // 0..3
    const int m    = blockIdx.y * GM + lane;
    const int kz   = blockIdx.z * GK;
    const int nw = __builtin_amdgcn_readfirstlane(blockIdx.x * GN + wave * 16);

    const float* xrow = x + (size_t)m * DD;

    float acc[16] = {};

    // prefetch first chunk
    float4 v0 = *(const float4*)&xrow[kz + wave * 8];
    float4 v1 = *(const float4*)&xrow[kz + wave * 8 + 4];

    for (int kc = kz; kc < kz + GK; kc += GBK) {
        __syncthreads();   // previous chunk's LDS reads complete
        xT[wave * 8 + 0][lane] = v0.x;
        xT[wave * 8 + 1][lane] = v0.y;
        xT[wave * 8 + 2][lane] = v0.z;
        xT[wave * 8 + 3][lane] = v0.w;
        xT[wave * 8 + 4][lane] = v1.x;
        xT[wave * 8 + 5][lane] = v1.y;
        xT[wave * 8 + 6][lane] = v1.z;
        xT[wave * 8 + 7][lane] = v1.w;
        __syncthreads();

        // issue next chunk's global loads now; in flight during compute
        if (kc + GBK < kz + GK) {
            v0 = *(const float4*)&xrow[kc + GBK + wave * 8];
            v1 = *(const float4*)&xrow[kc + GBK + wave * 8 + 4];
        }

        const float* th = &theta[(size_t)kc * NCOL + nw];
#pragma unroll 4
        for (int kk = 0; kk < GBK; ++kk) {
            const float a = xT[kk][lane];
#pragma unroll
            for (int j = 0; j < 16; ++j)
                acc[j] += a * th[(size_t)kk * NCOL + j];   // wave-uniform -> s_load
        }
    }

    float* dst = part + (size_t)blockIdx.z * (BSZ * NCOL) + (size_t)m * NCOL + nw;
    *(float4*)&dst[0]  = make_float4(acc[0],  acc[1],  acc[2],  acc[3]);
    *(float4*)&dst[4]  = make_float4(acc[4],  acc[5],  acc[6],  acc[7]);
    *(float4*)&dst[8]  = make_float4(acc[8],  acc[9],  acc[10], acc[11]);
    *(float4*)&dst[12] = make_float4(acc[12], acc[13], acc[14], acc[15]);
}

// ---------------------------------------------------------------------------
// Kernel 3: reduce 16 split-K partials, fold scale = exp(lws)/norm * log2e.
// ---------------------------------------------------------------------------
__global__ __launch_bounds__(256) void reduce_kernel(const float* __restrict__ part,
                                                     const float* __restrict__ norm,
                                                     const float* __restrict__ lws,
                                                     float* __restrict__ actv) {
    int i   = blockIdx.x * 256 + threadIdx.x;   // 0..327679
    int col = i % NCOL;
    float s = 0.f;
#pragma unroll
    for (int q = 0; q < KSPLIT; ++q)
        s += part[(size_t)q * (BSZ * NCOL) + i];
    const float scale = __builtin_amdgcn_exp2f(lws[col] * LOG2E) *
                        __builtin_amdgcn_rsqf(norm[col]) * LOG2E;
    actv[i] = s * scale;
}

// ---------------------------------------------------------------------------
// Kernel 4: pairwise L1 -> exp2 -> partial rowsum over 64-wide b2 chunk,
// coalesced f_part stores (NO device-scope atomics: those write through to
// HBM on non-coherent-L2 gfx950 -- measured 32B/atomic, +30us).
// Block = 128 threads, 4 b-rows each. grid (k=128, q=8) = 1024 blocks.
// ---------------------------------------------------------------------------
__global__ __launch_bounds__(128) void pairwise_kernel(const float* __restrict__ actv,
                                                       float* __restrict__ f_part) {
    const int k   = blockIdx.x;    // 0..127
    const int q   = blockIdx.y;    // 0..7
    const int tid = threadIdx.x;   // 0..127

    __shared__ float sB[64][8];    // 2 KiB, rows 32B-aligned

    for (int i = tid; i < 64 * PP; i += 128) {   // 320 entries, 3 iterations
        int r = i / PP;
        int p = i - r * PP;
        sB[r][p] = actv[(size_t)(q * 64 + r) * NCOL + k * PP + p];
    }

    float a[4][PP];
#pragma unroll
    for (int r = 0; r < 4; ++r) {
        const float* ap = &actv[(size_t)(tid + r * 128) * NCOL + k * PP];
#pragma unroll
        for (int p = 0; p < PP; ++p) a[r][p] = ap[p];
    }
    __syncthreads();

    float acc[4] = {0.f, 0.f, 0.f, 0.f};
#pragma unroll 2
    for (int j = 0; j < 64; ++j) {
        const float4 v  = *(const float4*)&sB[j][0];
        const float  v4 = sB[j][4];
#pragma unroll
        for (int r = 0; r < 4; ++r) {
            float s = fabsf(a[r][0] - v.x) + fabsf(a[r][1] - v.y) +
                      fabsf(a[r][2] - v.z) + fabsf(a[r][3] - v.w) +
                      fabsf(a[r][4] - v4);
            acc[r] += __builtin_amdgcn_exp2f(-s);   // actv pre-scaled by log2e
        }
    }

    float* fp = f_part + ((size_t)q * KK + k) * BSZ;
#pragma unroll
    for (int r = 0; r < 4; ++r)
        fp[tid + r * 128] = acc[r];
}

// ---------------------------------------------------------------------------
// Kernel 5: slim epilogue -- reduce f_part (8 q-chunks, L2-resident 2MB)
// into out[:, D:]. 256 blocks x 256 threads; f_part reads coalesced in b.
// ---------------------------------------------------------------------------
__global__ __launch_bounds__(256) void freduce_kernel(const float* __restrict__ f_part,
                                                      const float* __restrict__ bias,
                                                      float* __restrict__ out) {
    int i = blockIdx.x * 256 + threadIdx.x;   // 0..65535
    int k = i >> 9;          // 0..127
    int b = i & 511;
    float s = 0.f;
#pragma unroll
    for (int q = 0; q < QSPLIT; ++q)
        s += f_part[((size_t)q * KK + k) * BSZ + b];
    out[(size_t)b * OUTW + DD + k] = s - 1.0f + bias[k];
}

// ---------------------------------------------------------------------------
extern "C" void kernel_launch(void* const* d_in, const int* in_sizes, int n_in,
                              void* d_out, int out_size, void* d_ws, size_t ws_size,
                              hipStream_t stream) {
    const float* x     = (const float*)d_in[0];   // [512, 2048]
    const float* theta = (const float*)d_in[1];   // [2048, 128, 5]
    const float* lws   = (const float*)d_in[2];   // [128, 5]
    const float* bias  = (const float*)d_in[3];   // [128]
    float* out = (float*)d_out;                   // [512, 2176]

    float* ws     = (float*)d_ws;
    float* norm   = ws + WS_NORM;
    float* actv   = ws + WS_ACTV;
    float* f_part = ws + WS_FPART;
    float* part   = ws + WS_PART;

    norm_kernel<<<80, 256, 0, stream>>>(theta, norm);
    gemm_kernel<<<dim3(NCOL / GN, BSZ / GM, KSPLIT + 1), 256, 0, stream>>>(x, theta, part, out);
    reduce_kernel<<<(BSZ * NCOL) / 256, 256, 0, stream>>>(part, norm, lws, actv);
    pairwise_kernel<<<dim3(KK, QSPLIT), 128, 0, stream>>>(actv, f_part);
    freduce_kernel<<<256, 256, 0, stream>>>(f_part, bias, out);
}

// Round 4
// 116.907 us; speedup vs baseline: 1.3134x; 1.0490x over previous
//
#include <hip/hip_runtime.h>
#include <math.h>

#define BSZ 512
#define DD 2048
#define KK 128
#define PP 5
#define NCOL (KK * PP)   // 640
#define OUTW (DD + KK)   // 2176
#define LOG2E 1.4426950408889634f

#define KSPLIT 8
#define GK (DD / KSPLIT) // 256 k-depth per split
#define QSPLIT 8         // pairwise b2 chunks

typedef __attribute__((ext_vector_type(8))) short bf16x8;
typedef __attribute__((ext_vector_type(4))) float f32x4;

// ws layout (floats):
#define WS_NORM 0
#define WS_ACTV (WS_NORM + NCOL)                      // 640
#define WS_FPART (WS_ACTV + BSZ * NCOL)               // 328320
#define WS_XB (WS_FPART + QSPLIT * KK * BSZ)          // 852608 (512*2048 ushort)
#define WS_THT (WS_XB + BSZ * DD / 2)                 // 1376896 (640*2048 ushort)
#define WS_PART (WS_THT + NCOL * DD / 2)              // 2032256
// part = 8*512*640 = 2,621,440 floats; total ~18.6 MB

__device__ inline ushort f2b(float f) {               // f32 -> bf16 RNE
    unsigned u = __float_as_uint(f);
    u += 0x7FFF + ((u >> 16) & 1);
    return (ushort)(u >> 16);
}

// ---------------------------------------------------------------------------
// Kernel 1 (prep): [0,80) norm = colsum theta^2; [80,400) theta -> bf16
// transposed [640 n][2048 k]; [400,656) x -> bf16 [512][2048].
// All three give MFMA-gemm contiguous-k operands.
// ---------------------------------------------------------------------------
__global__ __launch_bounds__(256) void prep_kernel(const float* __restrict__ theta,
                                                   const float* __restrict__ x,
                                                   float* __restrict__ norm,
                                                   ushort* __restrict__ thT,
                                                   ushort* __restrict__ xb) {
    __shared__ float partial[32][8];
    __shared__ ushort sT[64][68];   // [n][k] tile; stride 68: write 8-way, read 2-way

    const int bid = blockIdx.x;
    const int t   = threadIdx.x;

    if (bid < 80) {                 // ---- norm ----
        const int c8  = bid * 8;
        const int col = c8 + (t & 7);
        const int g   = t >> 3;
        const float* p = theta + (size_t)g * NCOL + col;
        float s = 0.f;
#pragma unroll
        for (int j = 0; j < 64; ++j) {
            float v = p[(size_t)j * 32 * NCOL];
            s += v * v;
        }
        partial[g][t & 7] = s;
        __syncthreads();
        if (t < 8) {
            float acc = 0.f;
#pragma unroll
            for (int gg = 0; gg < 32; ++gg) acc += partial[gg][t];
            norm[c8 + t] = acc;
        }
    } else if (bid < 400) {         // ---- theta transpose+convert, 64x64 tiles ----
        const int tb    = bid - 80;        // 0..319 = 32 ktiles x 10 ntiles
        const int kz    = (tb & 31) * 64;
        const int nz    = (tb >> 5) * 64;
        const int c4    = t & 15;          // n-quad
        const int rbase = t >> 4;          // k-row base
#pragma unroll
        for (int i = 0; i < 4; ++i) {
            int r = rbase + i * 16;
            float4 v = *(const float4*)&theta[(size_t)(kz + r) * NCOL + nz + c4 * 4];
            sT[c4 * 4 + 0][r] = f2b(v.x);
            sT[c4 * 4 + 1][r] = f2b(v.y);
            sT[c4 * 4 + 2][r] = f2b(v.z);
            sT[c4 * 4 + 3][r] = f2b(v.w);
        }
        __syncthreads();
#pragma unroll
        for (int i = 0; i < 2; ++i) {
            int slot = t + i * 256;
            int rr   = slot >> 3;          // n row 0..63
            int cc   = (slot & 7) * 8;     // k col
            ushort4 w0 = *(const ushort4*)&sT[rr][cc];
            ushort4 w1 = *(const ushort4*)&sT[rr][cc + 4];
            ushort* dst = &thT[(size_t)(nz + rr) * DD + kz + cc];
            *(ushort4*)&dst[0] = w0;
            *(ushort4*)&dst[4] = w1;
        }
    } else {                        // ---- x convert ----
        const int b2 = bid - 400;          // 0..255
#pragma unroll
        for (int i = 0; i < 4; ++i) {
            int base = b2 * 4096 + i * 1024 + t * 4;
            float4 v = *(const float4*)&x[base];
            ushort4 w;
            w.x = f2b(v.x); w.y = f2b(v.y); w.z = f2b(v.z); w.w = f2b(v.w);
            *(ushort4*)&xb[base] = w;
        }
    }
}

// ---------------------------------------------------------------------------
// Kernel 2: split-K MFMA GEMM (bf16 in, f32 acc). Block 64m x 64n, 4 waves
// 2x2, each wave 32x32 via 4x mfma_f32_16x16x32_bf16 per 32-k step.
// GK=256 in 2 chunks of 128, reg-prefetched. A/B frags: row=lane&15,
// 8 contiguous k at (lane>>4)*8 (k-map shared by A/B -> permutation-safe);
// C/D: col=lane&15, row=(lane>>4)*4+reg [m89-verified].
// z == KSPLIT slice streams x -> out[:, :D] (overlapped BW work).
// ---------------------------------------------------------------------------
__global__ __launch_bounds__(256) void gemm_kernel(const ushort* __restrict__ xb,
                                                   const ushort* __restrict__ thT,
                                                   float* __restrict__ part,
                                                   const float* __restrict__ x,
                                                   float* __restrict__ out) {
    __shared__ ushort lA[64][136];   // pad 136: stage ~2-way, frag read 2-way
    __shared__ ushort lB[64][136];   // 34 KiB total

    if (blockIdx.z == KSPLIT) {
        const int bid = blockIdx.y * 10 + blockIdx.x;   // 0..79
        for (int i = bid * 256 + threadIdx.x; i < BSZ * (DD / 4); i += 80 * 256) {
            int r = i >> 9;
            int c = i & 511;
            float4 v = *(const float4*)&x[(size_t)r * DD + c * 4];
            *(float4*)&out[(size_t)r * OUTW + c * 4] = v;
        }
        return;
    }

    const int t    = threadIdx.x;
    const int lane = t & 63;
    const int wave = t >> 6;
    const int bn   = blockIdx.x * 64;
    const int bm   = blockIdx.y * 64;
    const int kz   = blockIdx.z * GK;

    const ushort* gA = xb  + (size_t)bm * DD + kz;
    const ushort* gB = thT + (size_t)bn * DD + kz;

    f32x4 acc[2][2] = {};

    uint4 va[4], vb[4];
#pragma unroll
    for (int i = 0; i < 4; ++i) {
        int slot = t + i * 256, rr = slot >> 4, ss = slot & 15;
        va[i] = *(const uint4*)&gA[(size_t)rr * DD + ss * 8];
        vb[i] = *(const uint4*)&gB[(size_t)rr * DD + ss * 8];
    }

    const int fr = lane & 15;
    const int g  = lane >> 4;
    const int mr = (wave >> 1) * 32 + fr;
    const int nr = (wave & 1) * 32 + fr;

#pragma unroll
    for (int c = 0; c < 2; ++c) {
        __syncthreads();
#pragma unroll
        for (int i = 0; i < 4; ++i) {
            int slot = t + i * 256, rr = slot >> 4, ss = slot & 15;
            *(uint4*)&lA[rr][ss * 8] = va[i];
            *(uint4*)&lB[rr][ss * 8] = vb[i];
        }
        __syncthreads();
        if (c == 0) {
#pragma unroll
            for (int i = 0; i < 4; ++i) {
                int slot = t + i * 256, rr = slot >> 4, ss = slot & 15;
                va[i] = *(const uint4*)&gA[(size_t)rr * DD + 128 + ss * 8];
                vb[i] = *(const uint4*)&gB[(size_t)rr * DD + 128 + ss * 8];
            }
        }
#pragma unroll
        for (int ks = 0; ks < 4; ++ks) {
            const int kc = ks * 32 + g * 8;
            bf16x8 a0 = *(const bf16x8*)&lA[mr][kc];
            bf16x8 a1 = *(const bf16x8*)&lA[mr + 16][kc];
            bf16x8 b0 = *(const bf16x8*)&lB[nr][kc];
            bf16x8 b1 = *(const bf16x8*)&lB[nr + 16][kc];
            acc[0][0] = __builtin_amdgcn_mfma_f32_16x16x32_bf16(a0, b0, acc[0][0], 0, 0, 0);
            acc[0][1] = __builtin_amdgcn_mfma_f32_16x16x32_bf16(a0, b1, acc[0][1], 0, 0, 0);
            acc[1][0] = __builtin_amdgcn_mfma_f32_16x16x32_bf16(a1, b0, acc[1][0], 0, 0, 0);
            acc[1][1] = __builtin_amdgcn_mfma_f32_16x16x32_bf16(a1, b1, acc[1][1], 0, 0, 0);
        }
    }

    float* base = part + (size_t)blockIdx.z * (BSZ * NCOL);
#pragma unroll
    for (int mt = 0; mt < 2; ++mt)
#pragma unroll
        for (int nt = 0; nt < 2; ++nt) {
            int row = bm + (wave >> 1) * 32 + mt * 16 + g * 4;
            int col = bn + (wave & 1) * 32 + nt * 16 + fr;
            float* dst = base + (size_t)row * NCOL + col;
#pragma unroll
            for (int reg = 0; reg < 4; ++reg)
                dst[(size_t)reg * NCOL] = acc[mt][nt][reg];
        }
}

// ---------------------------------------------------------------------------
// Kernel 3: reduce 8 split-K partials, fold scale = exp(lws)/norm * log2e.
// ---------------------------------------------------------------------------
__global__ __launch_bounds__(256) void reduce_kernel(const float* __restrict__ part,
                                                     const float* __restrict__ norm,
                                                     const float* __restrict__ lws,
                                                     float* __restrict__ actv) {
    int i   = blockIdx.x * 256 + threadIdx.x;   // 0..327679
    int col = i % NCOL;
    float s = 0.f;
#pragma unroll
    for (int q = 0; q < KSPLIT; ++q)
        s += part[(size_t)q * (BSZ * NCOL) + i];
    const float scale = __builtin_amdgcn_exp2f(lws[col] * LOG2E) *
                        __builtin_amdgcn_rsqf(norm[col]) * LOG2E;
    actv[i] = s * scale;
}

// ---------------------------------------------------------------------------
// Kernel 4: pairwise L1 -> exp2 -> partial rowsum over 64-wide b2 chunk,
// coalesced f_part stores (NO device-scope atomics: write-through to HBM
// on non-coherent-L2 gfx950 -- measured 32B/atomic, +30us in r2).
// ---------------------------------------------------------------------------
__global__ __launch_bounds__(128) void pairwise_kernel(const float* __restrict__ actv,
                                                       float* __restrict__ f_part) {
    const int k   = blockIdx.x;
    const int q   = blockIdx.y;
    const int tid = threadIdx.x;

    __shared__ float sB[64][8];

    for (int i = tid; i < 64 * PP; i += 128) {
        int r = i / PP;
        int p = i - r * PP;
        sB[r][p] = actv[(size_t)(q * 64 + r) * NCOL + k * PP + p];
    }

    float a[4][PP];
#pragma unroll
    for (int r = 0; r < 4; ++r) {
        const float* ap = &actv[(size_t)(tid + r * 128) * NCOL + k * PP];
#pragma unroll
        for (int p = 0; p < PP; ++p) a[r][p] = ap[p];
    }
    __syncthreads();

    float acc[4] = {0.f, 0.f, 0.f, 0.f};
#pragma unroll 2
    for (int j = 0; j < 64; ++j) {
        const float4 v  = *(const float4*)&sB[j][0];
        const float  v4 = sB[j][4];
#pragma unroll
        for (int r = 0; r < 4; ++r) {
            float s = fabsf(a[r][0] - v.x) + fabsf(a[r][1] - v.y) +
                      fabsf(a[r][2] - v.z) + fabsf(a[r][3] - v.w) +
                      fabsf(a[r][4] - v4);
            acc[r] += __builtin_amdgcn_exp2f(-s);   // actv pre-scaled by log2e
        }
    }

    float* fp = f_part + ((size_t)q * KK + k) * BSZ;
#pragma unroll
    for (int r = 0; r < 4; ++r)
        fp[tid + r * 128] = acc[r];
}

// ---------------------------------------------------------------------------
// Kernel 5: reduce f_part (L2-resident 2MB) into out[:, D:].
// ---------------------------------------------------------------------------
__global__ __launch_bounds__(256) void freduce_kernel(const float* __restrict__ f_part,
                                                      const float* __restrict__ bias,
                                                      float* __restrict__ out) {
    int i = blockIdx.x * 256 + threadIdx.x;   // 0..65535
    int k = i >> 9;
    int b = i & 511;
    float s = 0.f;
#pragma unroll
    for (int q = 0; q < QSPLIT; ++q)
        s += f_part[((size_t)q * KK + k) * BSZ + b];
    out[(size_t)b * OUTW + DD + k] = s - 1.0f + bias[k];
}

// ---------------------------------------------------------------------------
extern "C" void kernel_launch(void* const* d_in, const int* in_sizes, int n_in,
                              void* d_out, int out_size, void* d_ws, size_t ws_size,
                              hipStream_t stream) {
    const float* x     = (const float*)d_in[0];   // [512, 2048]
    const float* theta = (const float*)d_in[1];   // [2048, 128, 5]
    const float* lws   = (const float*)d_in[2];   // [128, 5]
    const float* bias  = (const float*)d_in[3];   // [128]
    float* out = (float*)d_out;                   // [512, 2176]

    float* ws     = (float*)d_ws;
    float* norm   = ws + WS_NORM;
    float* actv   = ws + WS_ACTV;
    float* f_part = ws + WS_FPART;
    ushort* xb    = (ushort*)(ws + WS_XB);
    ushort* thT   = (ushort*)(ws + WS_THT);
    float* part   = ws + WS_PART;

    prep_kernel<<<656, 256, 0, stream>>>(theta, x, norm, thT, xb);
    gemm_kernel<<<dim3(NCOL / 64, BSZ / 64, KSPLIT + 1), 256, 0, stream>>>(xb, thT, part, x, out);
    reduce_kernel<<<(BSZ * NCOL) / 256, 256, 0, stream>>>(part, norm, lws, actv);
    pairwise_kernel<<<dim3(KK, QSPLIT), 128, 0, stream>>>(actv, f_part);
    freduce_kernel<<<256, 256, 0, stream>>>(f_part, bias, out);
}